// Round 4
// baseline (189.133 us; speedup 1.0000x reference)
//
#include <hip/hip_runtime.h>
#include <hip/hip_cooperative_groups.h>
#include <math.h>

namespace cg = cooperative_groups;

#define N_ATOMS 8192
#define NGRAPH  32
#define HDIM    64
#define KTOT    728
#define TWO_PI  6.28318530717958647692f

__device__ __forceinline__ float silu_f(float x) {
    return x / (1.0f + expf(-x));
}

__device__ __forceinline__ int lower_bound_batch(const int* __restrict__ batch, int v) {
    int lo = 0, hi = N_ATOMS;
    while (lo < hi) {
        int mid = (lo + hi) >> 1;
        if (batch[mid] < v) lo = mid + 1; else hi = mid;
    }
    return lo;
}

__device__ __forceinline__ void inv3x3(const float* __restrict__ c, float* iv, float* detOut) {
    float a00 = c[0], a01 = c[1], a02 = c[2];
    float a10 = c[3], a11 = c[4], a12 = c[5];
    float a20 = c[6], a21 = c[7], a22 = c[8];
    float c00 = a11 * a22 - a12 * a21;
    float c01 = a12 * a20 - a10 * a22;
    float c02 = a10 * a21 - a11 * a20;
    float det = a00 * c00 + a01 * c01 + a02 * c02;
    float r = 1.0f / det;
    iv[0] = c00 * r; iv[1] = (a02 * a21 - a01 * a22) * r; iv[2] = (a01 * a12 - a02 * a11) * r;
    iv[3] = c01 * r; iv[4] = (a00 * a22 - a02 * a20) * r; iv[5] = (a02 * a10 - a00 * a12) * r;
    iv[6] = c02 * r; iv[7] = (a01 * a20 - a00 * a21) * r; iv[8] = (a00 * a11 - a01 * a10) * r;
    *detOut = det;
}

// per-k MLP weight (shared by fused + fallback paths); returns w/(2*vol)
__device__ __forceinline__ float mlp_weight_full(
    int k, const float* iv, float vol,
    const float* __restrict__ W1, const float* __restrict__ b1,
    const float* __restrict__ W2, const float* __restrict__ b2,
    const float* __restrict__ W3, const float* __restrict__ b3)
{
    int idx = (k < 364) ? k : k + 1;
    float fi = (float)(idx / 81 - 4);
    float fj = (float)((idx / 9) % 9 - 4);
    float fl = (float)(idx % 9 - 4);
    float kx = TWO_PI * (fi * iv[0] + fj * iv[3] + fl * iv[6]);
    float ky = TWO_PI * (fi * iv[1] + fj * iv[4] + fl * iv[7]);
    float kz = TWO_PI * (fi * iv[2] + fj * iv[5] + fl * iv[8]);
    float kn = sqrtf(kx * kx + ky * ky + kz * kz);
    float sk = fmaxf(kn, 1e-6f);
    float x0 = log1pf(sk);
    float f0 = x0, f1 = x0 * x0, f2 = 1.0f / sk;

    float h1v[HDIM];
    #pragma unroll
    for (int j = 0; j < HDIM; ++j) {
        float a = b1[j] + f0 * W1[j] + f1 * W1[64 + j] + f2 * W1[128 + j];
        h1v[j] = silu_f(a);
    }
    float mlp = b3[0];
    for (int half = 0; half < 2; ++half) {
        float acc[32];
        #pragma unroll
        for (int j = 0; j < 32; ++j) acc[j] = b2[half * 32 + j];
        for (int i = 0; i < HDIM; ++i) {
            float h = h1v[i];
            const float* w2row = W2 + i * 64 + half * 32;
            #pragma unroll
            for (int j = 0; j < 32; ++j) acc[j] = fmaf(h, w2row[j], acc[j]);
        }
        #pragma unroll
        for (int j = 0; j < 32; ++j) mlp += silu_f(acc[j]) * W3[half * 32 + j];
    }
    float sc = (mlp > 20.0f) ? mlp : log1pf(expf(mlp));
    float w = (12.566370614359172954f / (sk * sk)) * sc;
    if (!(kn > 1e-6f)) w = 0.0f;
    return w / (2.0f * vol);
}

// =================== fused cooperative kernel ===================
// grid = 448 blocks x 256 threads
//   blocks [0,256):   structure factors, (b = bid>>3, kslice = bid&7), 91 k each
//   blocks [256,448): per-(b,k) MLP 2-way split (46592 tasks) + zero d_out
//   grid.sync()
//   blocks [0,288):   potential, (b = bid/9, plane p = bid%9), atomicAdd -> out
#define CH 32
__global__ __launch_bounds__(256) void kFused(
    const float* __restrict__ cell, const float* __restrict__ pos,
    const int* __restrict__ batch, const float* __restrict__ source,
    const float* __restrict__ W1, const float* __restrict__ b1,
    const float* __restrict__ W2, const float* __restrict__ b2,
    const float* __restrict__ W3, const float* __restrict__ b3,
    float* __restrict__ wbuf, float* __restrict__ Sc, float* __restrict__ Ss,
    float* __restrict__ out)
{
    __shared__ float2 tab[CH][3][9];    // cos/sin(m*p_d), m in [-4,4]
    __shared__ float4 srcs[CH];
    __shared__ float  part[91 * 8];     // h=1 partial S for combine
    __shared__ float  lw[81];
    __shared__ float4 lSc[81];
    __shared__ float4 lSs[81];

    int bid = blockIdx.x;
    int tid = threadIdx.x;

    if (bid < 256) {
        // ---------------- phase B: structure factors ----------------
        int b = bid >> 3;
        int kslice = bid & 7;
        bool active = (tid < 182);
        int kl = active ? ((tid < 91) ? tid : tid - 91) : 0;
        int h  = (tid >= 91) ? 1 : 0;
        int k  = kslice * 91 + kl;
        int idx = (k < 364) ? k : k + 1;
        int ip4 = idx / 81;
        int jp4 = (idx / 9) % 9;
        int lp4 = idx % 9;

        int s0 = lower_bound_batch(batch, b);
        int e0 = lower_bound_batch(batch, b + 1);

        float iv[9]; float det;
        inv3x3(cell + b * 9, iv, &det);

        float4 accC = make_float4(0.f, 0.f, 0.f, 0.f);
        float4 accS = make_float4(0.f, 0.f, 0.f, 0.f);

        for (int base = s0; base < e0; base += CH) {
            int cnt = min(CH, e0 - base);
            __syncthreads();
            if (tid < 96) {
                int a = tid & 31, d = tid >> 5;
                if (a < cnt) {
                    int n = base + a;
                    float px = pos[n * 3], py = pos[n * 3 + 1], pz = pos[n * 3 + 2];
                    float p = TWO_PI * (px * iv[d] + py * iv[3 + d] + pz * iv[6 + d]);
                    float s1, c1; sincosf(p, &s1, &c1);
                    float c2 = c1 * c1 - s1 * s1, s2 = 2.f * c1 * s1;
                    float c3 = c2 * c1 - s2 * s1, s3 = c2 * s1 + s2 * c1;
                    float c4 = c2 * c2 - s2 * s2, s4 = 2.f * c2 * s2;
                    tab[a][d][4] = make_float2(1.f, 0.f);
                    tab[a][d][5] = make_float2(c1, s1);
                    tab[a][d][3] = make_float2(c1, -s1);
                    tab[a][d][6] = make_float2(c2, s2);
                    tab[a][d][2] = make_float2(c2, -s2);
                    tab[a][d][7] = make_float2(c3, s3);
                    tab[a][d][1] = make_float2(c3, -s3);
                    tab[a][d][8] = make_float2(c4, s4);
                    tab[a][d][0] = make_float2(c4, -s4);
                }
            } else if (tid < 128) {
                int a = tid - 96;
                if (a < cnt) srcs[a] = ((const float4*)source)[base + a];
            }
            __syncthreads();

            if (active) {
                int c0 = (cnt + 1) >> 1;
                int lo = h ? c0 : 0;
                int hiA = h ? cnt : c0;
                for (int a = lo; a < hiA; ++a) {
                    float2 ti = tab[a][0][ip4];
                    float2 tj = tab[a][1][jp4];
                    float2 tl = tab[a][2][lp4];
                    float c12 = ti.x * tj.x - ti.y * tj.y;
                    float s12 = ti.x * tj.y + ti.y * tj.x;
                    float cv = c12 * tl.x - s12 * tl.y;
                    float sv = c12 * tl.y + s12 * tl.x;
                    float4 s = srcs[a];
                    accC.x = fmaf(s.x, cv, accC.x); accC.y = fmaf(s.y, cv, accC.y);
                    accC.z = fmaf(s.z, cv, accC.z); accC.w = fmaf(s.w, cv, accC.w);
                    accS.x = fmaf(s.x, sv, accS.x); accS.y = fmaf(s.y, sv, accS.y);
                    accS.z = fmaf(s.z, sv, accS.z); accS.w = fmaf(s.w, sv, accS.w);
                }
            }
        }
        __syncthreads();
        if (active && h == 1) {
            int o = kl * 8;
            part[o + 0] = accC.x; part[o + 1] = accC.y; part[o + 2] = accC.z; part[o + 3] = accC.w;
            part[o + 4] = accS.x; part[o + 5] = accS.y; part[o + 6] = accS.z; part[o + 7] = accS.w;
        }
        __syncthreads();
        if (active && h == 0) {
            int o = kl * 8;
            accC.x += part[o + 0]; accC.y += part[o + 1]; accC.z += part[o + 2]; accC.w += part[o + 3];
            accS.x += part[o + 4]; accS.y += part[o + 5]; accS.z += part[o + 6]; accS.w += part[o + 7];
            ((float4*)Sc)[b * KTOT + k] = accC;
            ((float4*)Ss)[b * KTOT + k] = accS;
        }
    } else {
        // ---------------- phase A: MLP weights (2-way split) + zero out ----------------
        int u = (bid - 256) * 256 + tid;
        if (u < 46592) {
            int q = u >> 1;
            int half = u & 1;
            int b = q / KTOT;
            int k = q - b * KTOT;

            float iv[9]; float det;
            inv3x3(cell + b * 9, iv, &det);
            float vol = fmaxf(fabsf(det), 1e-6f);

            int idx = (k < 364) ? k : k + 1;
            float fi = (float)(idx / 81 - 4);
            float fj = (float)((idx / 9) % 9 - 4);
            float fl = (float)(idx % 9 - 4);
            float kx = TWO_PI * (fi * iv[0] + fj * iv[3] + fl * iv[6]);
            float ky = TWO_PI * (fi * iv[1] + fj * iv[4] + fl * iv[7]);
            float kz = TWO_PI * (fi * iv[2] + fj * iv[5] + fl * iv[8]);
            float kn = sqrtf(kx * kx + ky * ky + kz * kz);
            float sk = fmaxf(kn, 1e-6f);
            float x0 = log1pf(sk);
            float f0 = x0, f1 = x0 * x0, f2 = 1.0f / sk;

            float h1v[HDIM];
            #pragma unroll
            for (int j = 0; j < HDIM; ++j) {
                float a = b1[j] + f0 * W1[j] + f1 * W1[64 + j] + f2 * W1[128 + j];
                h1v[j] = silu_f(a);
            }
            float partial = (half == 0) ? b3[0] : 0.0f;
            {
                float acc[32];
                #pragma unroll
                for (int j = 0; j < 32; ++j) acc[j] = b2[half * 32 + j];
                for (int i = 0; i < HDIM; ++i) {
                    float hh = h1v[i];
                    const float* w2row = W2 + i * 64 + half * 32;
                    #pragma unroll
                    for (int j = 0; j < 32; ++j) acc[j] = fmaf(hh, w2row[j], acc[j]);
                }
                #pragma unroll
                for (int j = 0; j < 32; ++j) partial += silu_f(acc[j]) * W3[half * 32 + j];
            }
            float mlp = partial + __shfl_xor(partial, 1);
            if (half == 0) {
                float sc = (mlp > 20.0f) ? mlp : log1pf(expf(mlp));
                float w = (12.566370614359172954f / (sk * sk)) * sc;
                if (!(kn > 1e-6f)) w = 0.0f;
                wbuf[b * KTOT + k] = w / (2.0f * vol);
            }
        } else if (u < 48640) {
            ((float4*)out)[u - 46592] = make_float4(0.f, 0.f, 0.f, 0.f);
        }
    }

    cg::this_grid().sync();

    if (bid < 288) {
        // ---------------- phase C: per-atom potential ----------------
        int b = bid / 9;
        int p = bid - b * 9;

        if (tid < 81) {
            int idx = p * 81 + tid;
            if (idx == 364) {
                lw[tid] = 0.f;
                lSc[tid] = make_float4(0.f, 0.f, 0.f, 0.f);
                lSs[tid] = make_float4(0.f, 0.f, 0.f, 0.f);
            } else {
                int k = idx - (idx > 364 ? 1 : 0);
                lw[tid]  = wbuf[b * KTOT + k];
                lSc[tid] = ((const float4*)Sc)[b * KTOT + k];
                lSs[tid] = ((const float4*)Ss)[b * KTOT + k];
            }
        }
        __syncthreads();

        int s0 = lower_bound_batch(batch, b);
        int e0 = lower_bound_batch(batch, b + 1);
        float fi = (float)(p - 4);

        float iv[9]; float det;
        inv3x3(cell + b * 9, iv, &det);

        for (int n = s0 + tid; n < e0; n += 256) {
            float px = pos[n * 3], py = pos[n * 3 + 1], pz = pos[n * 3 + 2];
            float p1 = TWO_PI * (px * iv[0] + py * iv[3] + pz * iv[6]);
            float p2 = TWO_PI * (px * iv[1] + py * iv[4] + pz * iv[7]);
            float p3 = TWO_PI * (px * iv[2] + py * iv[5] + pz * iv[8]);
            float4 s = ((const float4*)source)[n];

            float si0, ci0; sincosf(fi * p1, &si0, &ci0);
            float s2, c2;   sincosf(p2, &s2, &c2);
            float s3, c3;   sincosf(p3, &s3, &c3);

            float c2_2 = c2 * c2 - s2 * s2, s2_2 = 2.f * c2 * s2;
            float c2_4 = c2_2 * c2_2 - s2_2 * s2_2, s2_4 = 2.f * c2_2 * s2_2;
            float c3_2 = c3 * c3 - s3 * s3, s3_2 = 2.f * c3 * s3;
            float c3_4 = c3_2 * c3_2 - s3_2 * s3_2, s3_4 = 2.f * c3_2 * s3_2;

            float ejc = ci0 * c2_4 + si0 * s2_4;
            float ejs = si0 * c2_4 - ci0 * s2_4;

            float acc = 0.f;
            for (int jj = 0; jj < 9; ++jj) {
                float fc = ejc * c3_4 + ejs * s3_4;
                float fs = ejs * c3_4 - ejc * s3_4;
                #pragma unroll
                for (int ll = 0; ll < 9; ++ll) {
                    int e = jj * 9 + ll;
                    float4 C  = lSc[e];
                    float4 S4 = lSs[e];
                    float w = lw[e];
                    float dc = s.x * C.x  + s.y * C.y  + s.z * C.z  + s.w * C.w;
                    float ds = s.x * S4.x + s.y * S4.y + s.z * S4.z + s.w * S4.w;
                    acc = fmaf(w, fmaf(fc, dc, fs * ds), acc);
                    float nfc = fc * c3 - fs * s3;
                    fs = fc * s3 + fs * c3;
                    fc = nfc;
                }
                float nejc = ejc * c2 - ejs * s2;
                ejs = ejc * s2 + ejs * c2;
                ejc = nejc;
            }
            atomicAdd(&out[n], acc);
        }
    }
}

// =================== fallback (non-cooperative) path ===================
__global__ __launch_bounds__(256) void kPrepFB(
    const float* __restrict__ cell, const float* __restrict__ pos,
    const int* __restrict__ batch,
    const float* __restrict__ W1, const float* __restrict__ b1,
    const float* __restrict__ W2, const float* __restrict__ b2,
    const float* __restrict__ W3, const float* __restrict__ b3,
    float* __restrict__ wout, float* __restrict__ frac2pi,
    float* __restrict__ Sc, float* __restrict__ Ss, float* __restrict__ out)
{
    int b = blockIdx.x;
    int y = blockIdx.y;
    int tid = threadIdx.x;
    int gt = (b * 3 + y) * 256 + tid;

    const float4 z4 = make_float4(0.f, 0.f, 0.f, 0.f);
    if (gt < 23296) { ((float4*)Sc)[gt] = z4; ((float4*)Ss)[gt] = z4; }
    if (gt < 2048) ((float4*)out)[gt] = z4;

    if (y == 0) {
        int n = b * 256 + tid;
        int bn = batch[n];
        float iv[9]; float det;
        inv3x3(cell + bn * 9, iv, &det);
        float px = pos[n * 3], py = pos[n * 3 + 1], pz = pos[n * 3 + 2];
        frac2pi[n * 3 + 0] = TWO_PI * (px * iv[0] + py * iv[3] + pz * iv[6]);
        frac2pi[n * 3 + 1] = TWO_PI * (px * iv[1] + py * iv[4] + pz * iv[7]);
        frac2pi[n * 3 + 2] = TWO_PI * (px * iv[2] + py * iv[5] + pz * iv[8]);
    }

    int k = y * 256 + tid;
    if (k >= KTOT) return;
    float iv[9]; float det;
    inv3x3(cell + b * 9, iv, &det);
    float vol = fmaxf(fabsf(det), 1e-6f);
    wout[b * KTOT + k] = mlp_weight_full(k, iv, vol, W1, b1, W2, b2, W3, b3);
}

__global__ __launch_bounds__(256) void kSFB(
    const float* __restrict__ frac2pi, const float* __restrict__ source,
    const int* __restrict__ batch,
    float* __restrict__ Sc, float* __restrict__ Ss)
{
    __shared__ float2 tab[64][3][9];
    __shared__ float4 srcs[64];

    int b = blockIdx.x;
    int tid = threadIdx.x;
    int k = blockIdx.y * 256 + tid;

    int s0 = lower_bound_batch(batch, b);
    int e0 = lower_bound_batch(batch, b + 1);
    int len = e0 - s0;
    int per = (len + 3) >> 2;
    int nb = s0 + blockIdx.z * per;
    int ne = min(nb + per, e0);

    bool active = (k < KTOT);
    int kk = active ? k : 0;
    int idx = (kk < 364) ? kk : kk + 1;
    int ip4 = idx / 81, jp4 = (idx / 9) % 9, lp4 = idx % 9;

    float4 accC = make_float4(0.f, 0.f, 0.f, 0.f);
    float4 accS = make_float4(0.f, 0.f, 0.f, 0.f);

    for (int base = nb; base < ne; base += 64) {
        int cnt = min(64, ne - base);
        __syncthreads();
        if (tid < 192) {
            int a = tid & 63, d = tid >> 6;
            if (a < cnt) {
                float p = frac2pi[(base + a) * 3 + d];
                float s1, c1; sincosf(p, &s1, &c1);
                float c2 = c1 * c1 - s1 * s1, s2 = 2.f * c1 * s1;
                float c3 = c2 * c1 - s2 * s1, s3 = c2 * s1 + s2 * c1;
                float c4 = c2 * c2 - s2 * s2, s4 = 2.f * c2 * s2;
                tab[a][d][4] = make_float2(1.f, 0.f);
                tab[a][d][5] = make_float2(c1, s1);
                tab[a][d][3] = make_float2(c1, -s1);
                tab[a][d][6] = make_float2(c2, s2);
                tab[a][d][2] = make_float2(c2, -s2);
                tab[a][d][7] = make_float2(c3, s3);
                tab[a][d][1] = make_float2(c3, -s3);
                tab[a][d][8] = make_float2(c4, s4);
                tab[a][d][0] = make_float2(c4, -s4);
            }
        } else {
            int a = tid - 192;
            if (a < cnt) srcs[a] = ((const float4*)source)[base + a];
        }
        __syncthreads();
        if (active) {
            for (int a = 0; a < cnt; ++a) {
                float2 ti = tab[a][0][ip4];
                float2 tj = tab[a][1][jp4];
                float2 tl = tab[a][2][lp4];
                float c12 = ti.x * tj.x - ti.y * tj.y;
                float s12 = ti.x * tj.y + ti.y * tj.x;
                float cv = c12 * tl.x - s12 * tl.y;
                float sv = c12 * tl.y + s12 * tl.x;
                float4 s = srcs[a];
                accC.x = fmaf(s.x, cv, accC.x); accC.y = fmaf(s.y, cv, accC.y);
                accC.z = fmaf(s.z, cv, accC.z); accC.w = fmaf(s.w, cv, accC.w);
                accS.x = fmaf(s.x, sv, accS.x); accS.y = fmaf(s.y, sv, accS.y);
                accS.z = fmaf(s.z, sv, accS.z); accS.w = fmaf(s.w, sv, accS.w);
            }
        }
    }
    if (active) {
        float* pc = Sc + (size_t)(b * KTOT + k) * 4;
        atomicAdd(pc + 0, accC.x); atomicAdd(pc + 1, accC.y);
        atomicAdd(pc + 2, accC.z); atomicAdd(pc + 3, accC.w);
        float* ps = Ss + (size_t)(b * KTOT + k) * 4;
        atomicAdd(ps + 0, accS.x); atomicAdd(ps + 1, accS.y);
        atomicAdd(ps + 2, accS.z); atomicAdd(ps + 3, accS.w);
    }
}

__global__ __launch_bounds__(256) void kPotFB(
    const float* __restrict__ frac2pi, const float* __restrict__ source,
    const int* __restrict__ batch, const float* __restrict__ wbuf,
    const float* __restrict__ Sc, const float* __restrict__ Ss,
    float* __restrict__ out)
{
    __shared__ float  lw[81];
    __shared__ float4 lSc[81];
    __shared__ float4 lSs[81];

    int b = blockIdx.x;
    int p = blockIdx.y;
    int tid = threadIdx.x;

    if (tid < 81) {
        int idx = p * 81 + tid;
        if (idx == 364) {
            lw[tid] = 0.f;
            lSc[tid] = make_float4(0.f, 0.f, 0.f, 0.f);
            lSs[tid] = make_float4(0.f, 0.f, 0.f, 0.f);
        } else {
            int k = idx - (idx > 364 ? 1 : 0);
            lw[tid]  = wbuf[b * KTOT + k];
            lSc[tid] = ((const float4*)Sc)[b * KTOT + k];
            lSs[tid] = ((const float4*)Ss)[b * KTOT + k];
        }
    }
    __syncthreads();

    int s0 = lower_bound_batch(batch, b);
    int e0 = lower_bound_batch(batch, b + 1);
    float fi = (float)(p - 4);

    for (int n = s0 + tid; n < e0; n += 256) {
        float p1 = frac2pi[n * 3 + 0];
        float p2 = frac2pi[n * 3 + 1];
        float p3 = frac2pi[n * 3 + 2];
        float4 s = ((const float4*)source)[n];

        float si0, ci0; sincosf(fi * p1, &si0, &ci0);
        float s2, c2;   sincosf(p2, &s2, &c2);
        float s3, c3;   sincosf(p3, &s3, &c3);

        float c2_2 = c2 * c2 - s2 * s2, s2_2 = 2.f * c2 * s2;
        float c2_4 = c2_2 * c2_2 - s2_2 * s2_2, s2_4 = 2.f * c2_2 * s2_2;
        float c3_2 = c3 * c3 - s3 * s3, s3_2 = 2.f * c3 * s3;
        float c3_4 = c3_2 * c3_2 - s3_2 * s3_2, s3_4 = 2.f * c3_2 * s3_2;

        float ejc = ci0 * c2_4 + si0 * s2_4;
        float ejs = si0 * c2_4 - ci0 * s2_4;

        float acc = 0.f;
        for (int jj = 0; jj < 9; ++jj) {
            float fc = ejc * c3_4 + ejs * s3_4;
            float fs = ejs * c3_4 - ejc * s3_4;
            #pragma unroll
            for (int ll = 0; ll < 9; ++ll) {
                int e = jj * 9 + ll;
                float4 C  = lSc[e];
                float4 S4 = lSs[e];
                float w = lw[e];
                float dc = s.x * C.x  + s.y * C.y  + s.z * C.z  + s.w * C.w;
                float ds = s.x * S4.x + s.y * S4.y + s.z * S4.z + s.w * S4.w;
                acc = fmaf(w, fmaf(fc, dc, fs * ds), acc);
                float nfc = fc * c3 - fs * s3;
                fs = fc * s3 + fs * c3;
                fc = nfc;
            }
            float nejc = ejc * c2 - ejs * s2;
            ejs = ejc * s2 + ejs * c2;
            ejc = nejc;
        }
        atomicAdd(&out[n], acc);
    }
}

extern "C" void kernel_launch(void* const* d_in, const int* in_sizes, int n_in,
                              void* d_out, int out_size, void* d_ws, size_t ws_size,
                              hipStream_t stream)
{
    const float* pos    = (const float*)d_in[0];
    const int*   batch  = (const int*)d_in[1];
    const float* cell   = (const float*)d_in[2];
    const float* source = (const float*)d_in[3];
    const float* W1 = (const float*)d_in[4];
    const float* b1 = (const float*)d_in[5];
    const float* W2 = (const float*)d_in[6];
    const float* b2 = (const float*)d_in[7];
    const float* W3 = (const float*)d_in[8];
    const float* b3 = (const float*)d_in[9];
    float* out = (float*)d_out;

    float* ws   = (float*)d_ws;
    float* wbuf = ws;                  // 23296 floats
    float* Sc   = ws + 23296;          // 93184 floats (byte off 93184, 16B aligned)
    float* Ss   = ws + 116480;         // 93184 floats
    float* frac = ws + 209664;         // 24576 floats (fallback only)

    void* args[] = {
        (void*)&cell, (void*)&pos, (void*)&batch, (void*)&source,
        (void*)&W1, (void*)&b1, (void*)&W2, (void*)&b2, (void*)&W3, (void*)&b3,
        (void*)&wbuf, (void*)&Sc, (void*)&Ss, (void*)&out
    };
    hipError_t err = hipLaunchCooperativeKernel((const void*)kFused,
                                                dim3(448), dim3(256),
                                                args, 0, stream);
    if (err != hipSuccess) {
        // deterministic fallback: round-3 3-kernel structure
        kPrepFB<<<dim3(NGRAPH, 3), 256, 0, stream>>>(cell, pos, batch,
            W1, b1, W2, b2, W3, b3, wbuf, frac, Sc, Ss, out);
        kSFB<<<dim3(NGRAPH, 3, 4), 256, 0, stream>>>(frac, source, batch, Sc, Ss);
        kPotFB<<<dim3(NGRAPH, 9), 256, 0, stream>>>(frac, source, batch, wbuf, Sc, Ss, out);
    }
}

// Round 5
// 134.148 us; speedup vs baseline: 1.4099x; 1.4099x over previous
//
#include <hip/hip_runtime.h>
#include <math.h>

#define N_ATOMS 8192
#define NGRAPH  32
#define KTOT    728
#define TWO_PI  6.28318530717958647692f
#define CH 32

__device__ __forceinline__ float silu_f(float x) {
    return x / (1.0f + expf(-x));
}

__device__ __forceinline__ int lower_bound_batch(const int* __restrict__ batch, int v) {
    int lo = 0, hi = N_ATOMS;
    while (lo < hi) {
        int mid = (lo + hi) >> 1;
        if (batch[mid] < v) lo = mid + 1; else hi = mid;
    }
    return lo;
}

__device__ __forceinline__ void inv3x3(const float* __restrict__ c, float* iv, float* detOut) {
    float a00 = c[0], a01 = c[1], a02 = c[2];
    float a10 = c[3], a11 = c[4], a12 = c[5];
    float a20 = c[6], a21 = c[7], a22 = c[8];
    float c00 = a11 * a22 - a12 * a21;
    float c01 = a12 * a20 - a10 * a22;
    float c02 = a10 * a21 - a11 * a20;
    float det = a00 * c00 + a01 * c01 + a02 * c02;
    float r = 1.0f / det;
    iv[0] = c00 * r; iv[1] = (a02 * a21 - a01 * a22) * r; iv[2] = (a01 * a12 - a02 * a11) * r;
    iv[3] = c01 * r; iv[4] = (a00 * a22 - a02 * a20) * r; iv[5] = (a02 * a10 - a00 * a12) * r;
    iv[6] = c02 * r; iv[7] = (a01 * a20 - a00 * a21) * r; iv[8] = (a00 * a11 - a01 * a10) * r;
    *detOut = det;
}

// =================== K1: structure factors (blocks 0..383) + MLP weights (384..575) ===================
// SF: b = bid/12, slice = bid%12, k = slice*64 + (tid&63), quarter h = tid>>6.
//     4-way atom split per k, LDS combine, single float4 store per (b,k). No atomics, no init.
// MLP: 46592 tasks = 23296 (b,k) x 2 output halves; no h1v array (h recomputed per i);
//      acc[32] only -> no spill. Pair combine via __shfl_xor. Tail zeroes d_out.
__global__ __launch_bounds__(256) void kMain(
    const float* __restrict__ cell, const float* __restrict__ pos,
    const int* __restrict__ batch, const float* __restrict__ source,
    const float* __restrict__ W1, const float* __restrict__ b1,
    const float* __restrict__ W2, const float* __restrict__ b2,
    const float* __restrict__ W3, const float* __restrict__ b3,
    float* __restrict__ wbuf, float* __restrict__ Sc, float* __restrict__ Ss,
    float* __restrict__ out)
{
    __shared__ float2 tab[CH][3][9];   // cos/sin(m*p_d), m in [-4,4]
    __shared__ float4 srcs[CH];
    __shared__ float4 partC[3][64];
    __shared__ float4 partS[3][64];

    int bid = blockIdx.x;
    int tid = threadIdx.x;

    if (bid < 384) {
        // ---------------- structure factors ----------------
        int b = bid / 12;
        int slice = bid - b * 12;
        int kl = tid & 63;
        int h = tid >> 6;               // 0..3, wave-uniform
        int k = slice * 64 + kl;
        bool kvalid = (k < KTOT);
        int kk = kvalid ? k : 0;
        int idx = (kk < 364) ? kk : kk + 1;
        int ip4 = idx / 81;
        int jp4 = (idx / 9) % 9;
        int lp4 = idx % 9;

        int s0 = lower_bound_batch(batch, b);
        int e0 = lower_bound_batch(batch, b + 1);

        float iv[9]; float det;
        inv3x3(cell + b * 9, iv, &det);

        float4 accC = make_float4(0.f, 0.f, 0.f, 0.f);
        float4 accS = make_float4(0.f, 0.f, 0.f, 0.f);

        for (int base = s0; base < e0; base += CH) {
            int cnt = min(CH, e0 - base);
            __syncthreads();
            if (tid < 96) {
                int a = tid & 31, d = tid >> 5;
                if (a < cnt) {
                    int n = base + a;
                    float px = pos[n * 3], py = pos[n * 3 + 1], pz = pos[n * 3 + 2];
                    float p = TWO_PI * (px * iv[d] + py * iv[3 + d] + pz * iv[6 + d]);
                    float s1, c1; sincosf(p, &s1, &c1);
                    float c2 = c1 * c1 - s1 * s1, s2 = 2.f * c1 * s1;
                    float c3 = c2 * c1 - s2 * s1, s3 = c2 * s1 + s2 * c1;
                    float c4 = c2 * c2 - s2 * s2, s4 = 2.f * c2 * s2;
                    tab[a][d][4] = make_float2(1.f, 0.f);
                    tab[a][d][5] = make_float2(c1, s1);
                    tab[a][d][3] = make_float2(c1, -s1);
                    tab[a][d][6] = make_float2(c2, s2);
                    tab[a][d][2] = make_float2(c2, -s2);
                    tab[a][d][7] = make_float2(c3, s3);
                    tab[a][d][1] = make_float2(c3, -s3);
                    tab[a][d][8] = make_float2(c4, s4);
                    tab[a][d][0] = make_float2(c4, -s4);
                }
            } else if (tid < 128) {
                int a = tid - 96;
                if (a < cnt) srcs[a] = ((const float4*)source)[base + a];
            }
            __syncthreads();

            if (kvalid) {
                for (int a = h; a < cnt; a += 4) {
                    float2 ti = tab[a][0][ip4];
                    float2 tj = tab[a][1][jp4];
                    float2 tl = tab[a][2][lp4];
                    float c12 = ti.x * tj.x - ti.y * tj.y;
                    float s12 = ti.x * tj.y + ti.y * tj.x;
                    float cv = c12 * tl.x - s12 * tl.y;
                    float sv = c12 * tl.y + s12 * tl.x;
                    float4 s = srcs[a];
                    accC.x = fmaf(s.x, cv, accC.x); accC.y = fmaf(s.y, cv, accC.y);
                    accC.z = fmaf(s.z, cv, accC.z); accC.w = fmaf(s.w, cv, accC.w);
                    accS.x = fmaf(s.x, sv, accS.x); accS.y = fmaf(s.y, sv, accS.y);
                    accS.z = fmaf(s.z, sv, accS.z); accS.w = fmaf(s.w, sv, accS.w);
                }
            }
        }

        __syncthreads();
        if (h > 0) {
            partC[h - 1][kl] = accC;
            partS[h - 1][kl] = accS;
        }
        __syncthreads();
        if (h == 0 && kvalid) {
            #pragma unroll
            for (int q = 0; q < 3; ++q) {
                float4 pc = partC[q][kl], ps = partS[q][kl];
                accC.x += pc.x; accC.y += pc.y; accC.z += pc.z; accC.w += pc.w;
                accS.x += ps.x; accS.y += ps.y; accS.z += ps.z; accS.w += ps.w;
            }
            ((float4*)Sc)[b * KTOT + k] = accC;
            ((float4*)Ss)[b * KTOT + k] = accS;
        }
    } else {
        // ---------------- MLP weights + zero out ----------------
        int u = (bid - 384) * 256 + tid;
        if (u < 46592) {
            int q = u >> 1;
            int half = u & 1;
            int b = q / KTOT;
            int k = q - b * KTOT;

            float iv[9]; float det;
            inv3x3(cell + b * 9, iv, &det);
            float vol = fmaxf(fabsf(det), 1e-6f);

            int idx = (k < 364) ? k : k + 1;
            float fi = (float)(idx / 81 - 4);
            float fj = (float)((idx / 9) % 9 - 4);
            float fl = (float)(idx % 9 - 4);
            float kx = TWO_PI * (fi * iv[0] + fj * iv[3] + fl * iv[6]);
            float ky = TWO_PI * (fi * iv[1] + fj * iv[4] + fl * iv[7]);
            float kz = TWO_PI * (fi * iv[2] + fj * iv[5] + fl * iv[8]);
            float kn = sqrtf(kx * kx + ky * ky + kz * kz);
            float sk = fmaxf(kn, 1e-6f);
            float x0 = log1pf(sk);
            float f0 = x0, f1 = x0 * x0, f2 = 1.0f / sk;

            float acc[32];
            #pragma unroll
            for (int j = 0; j < 32; ++j) acc[j] = b2[half * 32 + j];
            for (int i = 0; i < 64; ++i) {
                float a = b1[i] + f0 * W1[i] + f1 * W1[64 + i] + f2 * W1[128 + i];
                float hh = silu_f(a);
                const float* w2row = W2 + i * 64 + half * 32;
                #pragma unroll
                for (int j = 0; j < 32; ++j) acc[j] = fmaf(hh, w2row[j], acc[j]);
            }
            float partial = (half == 0) ? b3[0] : 0.0f;
            #pragma unroll
            for (int j = 0; j < 32; ++j) partial += silu_f(acc[j]) * W3[half * 32 + j];

            float mlp = partial + __shfl_xor(partial, 1);
            if (half == 0) {
                float sc = (mlp > 20.0f) ? mlp : log1pf(expf(mlp));
                float w = (12.566370614359172954f / (sk * sk)) * sc;
                if (!(kn > 1e-6f)) w = 0.0f;
                wbuf[b * KTOT + k] = w / (2.0f * vol);
            }
        } else if (u < 48640) {
            ((float4*)out)[u - 46592] = make_float4(0.f, 0.f, 0.f, 0.f);
        }
    }
}

// =================== K2: per-atom potential via i-plane recurrences ===================
__global__ __launch_bounds__(256) void kPot(
    const float* __restrict__ cell, const float* __restrict__ pos,
    const int* __restrict__ batch, const float* __restrict__ source,
    const float* __restrict__ wbuf,
    const float* __restrict__ Sc, const float* __restrict__ Ss,
    float* __restrict__ out)
{
    __shared__ float  lw[81];
    __shared__ float4 lSc[81];
    __shared__ float4 lSs[81];

    int b = blockIdx.x;
    int p = blockIdx.y;     // plane 0..8 -> i = p-4
    int tid = threadIdx.x;

    if (tid < 81) {
        int idx = p * 81 + tid;
        if (idx == 364) {   // excluded k=0 point
            lw[tid] = 0.f;
            lSc[tid] = make_float4(0.f, 0.f, 0.f, 0.f);
            lSs[tid] = make_float4(0.f, 0.f, 0.f, 0.f);
        } else {
            int k = idx - (idx > 364 ? 1 : 0);
            lw[tid]  = wbuf[b * KTOT + k];
            lSc[tid] = ((const float4*)Sc)[b * KTOT + k];
            lSs[tid] = ((const float4*)Ss)[b * KTOT + k];
        }
    }
    __syncthreads();

    int s0 = lower_bound_batch(batch, b);
    int e0 = lower_bound_batch(batch, b + 1);
    float fi = (float)(p - 4);

    float iv[9]; float det;
    inv3x3(cell + b * 9, iv, &det);

    for (int n = s0 + tid; n < e0; n += 256) {
        float px = pos[n * 3], py = pos[n * 3 + 1], pz = pos[n * 3 + 2];
        float p1 = TWO_PI * (px * iv[0] + py * iv[3] + pz * iv[6]);
        float p2 = TWO_PI * (px * iv[1] + py * iv[4] + pz * iv[7]);
        float p3 = TWO_PI * (px * iv[2] + py * iv[5] + pz * iv[8]);
        float4 s = ((const float4*)source)[n];

        float si0, ci0; sincosf(fi * p1, &si0, &ci0);
        float s2, c2;   sincosf(p2, &s2, &c2);
        float s3, c3;   sincosf(p3, &s3, &c3);

        float c2_2 = c2 * c2 - s2 * s2, s2_2 = 2.f * c2 * s2;
        float c2_4 = c2_2 * c2_2 - s2_2 * s2_2, s2_4 = 2.f * c2_2 * s2_2;
        float c3_2 = c3 * c3 - s3 * s3, s3_2 = 2.f * c3 * s3;
        float c3_4 = c3_2 * c3_2 - s3_2 * s3_2, s3_4 = 2.f * c3_2 * s3_2;

        float ejc = ci0 * c2_4 + si0 * s2_4;   // rot(i*p1) * rot(-4*p2)
        float ejs = si0 * c2_4 - ci0 * s2_4;

        float acc = 0.f;
        for (int jj = 0; jj < 9; ++jj) {
            float fc = ejc * c3_4 + ejs * s3_4; // ej * rot(-4*p3)
            float fs = ejs * c3_4 - ejc * s3_4;
            #pragma unroll
            for (int ll = 0; ll < 9; ++ll) {
                int e = jj * 9 + ll;
                float4 C  = lSc[e];
                float4 S4 = lSs[e];
                float w = lw[e];
                float dc = s.x * C.x  + s.y * C.y  + s.z * C.z  + s.w * C.w;
                float ds = s.x * S4.x + s.y * S4.y + s.z * S4.z + s.w * S4.w;
                acc = fmaf(w, fmaf(fc, dc, fs * ds), acc);
                float nfc = fc * c3 - fs * s3;
                fs = fc * s3 + fs * c3;
                fc = nfc;
            }
            float nejc = ejc * c2 - ejs * s2;
            ejs = ejc * s2 + ejs * c2;
            ejc = nejc;
        }
        atomicAdd(&out[n], acc);
    }
}

extern "C" void kernel_launch(void* const* d_in, const int* in_sizes, int n_in,
                              void* d_out, int out_size, void* d_ws, size_t ws_size,
                              hipStream_t stream)
{
    const float* pos    = (const float*)d_in[0];
    const int*   batch  = (const int*)d_in[1];
    const float* cell   = (const float*)d_in[2];
    const float* source = (const float*)d_in[3];
    const float* W1 = (const float*)d_in[4];
    const float* b1 = (const float*)d_in[5];
    const float* W2 = (const float*)d_in[6];
    const float* b2 = (const float*)d_in[7];
    const float* W3 = (const float*)d_in[8];
    const float* b3 = (const float*)d_in[9];
    float* out = (float*)d_out;

    float* ws   = (float*)d_ws;
    float* wbuf = ws;                  // 23296 floats
    float* Sc   = ws + 23296;          // 93184 floats (byte offset 93184, 16B aligned)
    float* Ss   = ws + 116480;         // 93184 floats

    kMain<<<dim3(576), 256, 0, stream>>>(cell, pos, batch, source,
        W1, b1, W2, b2, W3, b3, wbuf, Sc, Ss, out);
    kPot<<<dim3(NGRAPH, 9), 256, 0, stream>>>(cell, pos, batch, source,
        wbuf, Sc, Ss, out);
}

// Round 6
// 120.365 us; speedup vs baseline: 1.5713x; 1.1145x over previous
//
#include <hip/hip_runtime.h>
#include <math.h>

#define N_ATOMS 8192
#define NGRAPH  32
#define KTOT    728
#define TWO_PI  6.28318530717958647692f
#define CH 32

__device__ __forceinline__ float silu_f(float x) {
    return x / (1.0f + expf(-x));
}

__device__ __forceinline__ int lower_bound_batch(const int* __restrict__ batch, int v) {
    int lo = 0, hi = N_ATOMS;
    while (lo < hi) {
        int mid = (lo + hi) >> 1;
        if (batch[mid] < v) lo = mid + 1; else hi = mid;
    }
    return lo;
}

__device__ __forceinline__ void inv3x3(const float* __restrict__ c, float* iv, float* detOut) {
    float a00 = c[0], a01 = c[1], a02 = c[2];
    float a10 = c[3], a11 = c[4], a12 = c[5];
    float a20 = c[6], a21 = c[7], a22 = c[8];
    float c00 = a11 * a22 - a12 * a21;
    float c01 = a12 * a20 - a10 * a22;
    float c02 = a10 * a21 - a11 * a20;
    float det = a00 * c00 + a01 * c01 + a02 * c02;
    float r = 1.0f / det;
    iv[0] = c00 * r; iv[1] = (a02 * a21 - a01 * a22) * r; iv[2] = (a01 * a12 - a02 * a11) * r;
    iv[3] = c01 * r; iv[4] = (a00 * a22 - a02 * a20) * r; iv[5] = (a02 * a10 - a00 * a12) * r;
    iv[6] = c02 * r; iv[7] = (a01 * a20 - a00 * a21) * r; iv[8] = (a00 * a11 - a01 * a10) * r;
    *detOut = det;
}

// =================== K1 ===================
// blocks [0,91):    MLP weights, 1 thread per (b,k). `half` is a sequential
//                   loop var -> all W1/W2/W3 indices are wave-uniform -> the
//                   compiler scalarizes weight loads (s_load + SGPR fma operand).
//                   DO NOT make `half` lane-dependent (round-5 regression: 47us).
// blocks [91,99):   zero d_out (2048 float4).
// blocks [99,483):  structure factors: b=(bid-99)/12, slice=%12, k=slice*64+(tid&63),
//                   4-way atom split (h=tid>>6), LDS combine, single float4 store.
__global__ __launch_bounds__(256) void kMain(
    const float* __restrict__ cell, const float* __restrict__ pos,
    const int* __restrict__ batch, const float* __restrict__ source,
    const float* __restrict__ W1, const float* __restrict__ b1,
    const float* __restrict__ W2, const float* __restrict__ b2,
    const float* __restrict__ W3, const float* __restrict__ b3,
    float* __restrict__ wbuf, float* __restrict__ Sc, float* __restrict__ Ss,
    float* __restrict__ out)
{
    __shared__ float2 tab[CH][3][9];   // cos/sin(m*p_d), m in [-4,4]
    __shared__ float4 srcs[CH];
    __shared__ float4 partC[3][64];
    __shared__ float4 partS[3][64];

    int bid = blockIdx.x;
    int tid = threadIdx.x;

    if (bid < 91) {
        // ---------------- MLP weights (uniform W2 access -> scalar loads) ----------------
        int u = bid * 256 + tid;
        if (u >= 23296) return;
        int b = u / KTOT;
        int k = u - b * KTOT;

        float iv[9]; float det;
        inv3x3(cell + b * 9, iv, &det);
        float vol = fmaxf(fabsf(det), 1e-6f);

        int idx = (k < 364) ? k : k + 1;   // skip (0,0,0)
        float fi = (float)(idx / 81 - 4);
        float fj = (float)((idx / 9) % 9 - 4);
        float fl = (float)(idx % 9 - 4);
        float kx = TWO_PI * (fi * iv[0] + fj * iv[3] + fl * iv[6]);
        float ky = TWO_PI * (fi * iv[1] + fj * iv[4] + fl * iv[7]);
        float kz = TWO_PI * (fi * iv[2] + fj * iv[5] + fl * iv[8]);
        float kn = sqrtf(kx * kx + ky * ky + kz * kz);
        float sk = fmaxf(kn, 1e-6f);
        float x0 = log1pf(sk);
        float f0 = x0, f1 = x0 * x0, f2 = 1.0f / sk;

        float h1v[64];
        #pragma unroll
        for (int j = 0; j < 64; ++j) {
            float a = b1[j] + f0 * W1[j] + f1 * W1[64 + j] + f2 * W1[128 + j];
            h1v[j] = silu_f(a);
        }
        float mlp = b3[0];
        for (int half = 0; half < 2; ++half) {   // sequential: keeps W2 index uniform
            float acc[32];
            #pragma unroll
            for (int j = 0; j < 32; ++j) acc[j] = b2[half * 32 + j];
            for (int i = 0; i < 64; ++i) {
                float h = h1v[i];
                const float* w2row = W2 + i * 64 + half * 32;
                #pragma unroll
                for (int j = 0; j < 32; ++j) acc[j] = fmaf(h, w2row[j], acc[j]);
            }
            #pragma unroll
            for (int j = 0; j < 32; ++j) mlp += silu_f(acc[j]) * W3[half * 32 + j];
        }
        float sc = (mlp > 20.0f) ? mlp : log1pf(expf(mlp));
        float w = (12.566370614359172954f / (sk * sk)) * sc;   // 4*pi/k^2 * scale
        if (!(kn > 1e-6f)) w = 0.0f;
        wbuf[b * KTOT + k] = w / (2.0f * vol);                 // fold 0.5/vol
    } else if (bid < 99) {
        // ---------------- zero d_out ----------------
        int gt = (bid - 91) * 256 + tid;
        ((float4*)out)[gt] = make_float4(0.f, 0.f, 0.f, 0.f);
    } else {
        // ---------------- structure factors ----------------
        int sfid = bid - 99;
        int b = sfid / 12;
        int slice = sfid - b * 12;
        int kl = tid & 63;
        int h = tid >> 6;               // 0..3, wave-uniform
        int k = slice * 64 + kl;
        bool kvalid = (k < KTOT);
        int kk = kvalid ? k : 0;
        int idx = (kk < 364) ? kk : kk + 1;
        int ip4 = idx / 81;
        int jp4 = (idx / 9) % 9;
        int lp4 = idx % 9;

        int s0 = lower_bound_batch(batch, b);
        int e0 = lower_bound_batch(batch, b + 1);

        float iv[9]; float det;
        inv3x3(cell + b * 9, iv, &det);

        float4 accC = make_float4(0.f, 0.f, 0.f, 0.f);
        float4 accS = make_float4(0.f, 0.f, 0.f, 0.f);

        for (int base = s0; base < e0; base += CH) {
            int cnt = min(CH, e0 - base);
            __syncthreads();
            if (tid < 96) {
                int a = tid & 31, d = tid >> 5;
                if (a < cnt) {
                    int n = base + a;
                    float px = pos[n * 3], py = pos[n * 3 + 1], pz = pos[n * 3 + 2];
                    float p = TWO_PI * (px * iv[d] + py * iv[3 + d] + pz * iv[6 + d]);
                    float s1, c1; sincosf(p, &s1, &c1);
                    float c2 = c1 * c1 - s1 * s1, s2 = 2.f * c1 * s1;
                    float c3 = c2 * c1 - s2 * s1, s3 = c2 * s1 + s2 * c1;
                    float c4 = c2 * c2 - s2 * s2, s4 = 2.f * c2 * s2;
                    tab[a][d][4] = make_float2(1.f, 0.f);
                    tab[a][d][5] = make_float2(c1, s1);
                    tab[a][d][3] = make_float2(c1, -s1);
                    tab[a][d][6] = make_float2(c2, s2);
                    tab[a][d][2] = make_float2(c2, -s2);
                    tab[a][d][7] = make_float2(c3, s3);
                    tab[a][d][1] = make_float2(c3, -s3);
                    tab[a][d][8] = make_float2(c4, s4);
                    tab[a][d][0] = make_float2(c4, -s4);
                }
            } else if (tid < 128) {
                int a = tid - 96;
                if (a < cnt) srcs[a] = ((const float4*)source)[base + a];
            }
            __syncthreads();

            if (kvalid) {
                for (int a = h; a < cnt; a += 4) {
                    float2 ti = tab[a][0][ip4];
                    float2 tj = tab[a][1][jp4];
                    float2 tl = tab[a][2][lp4];
                    float c12 = ti.x * tj.x - ti.y * tj.y;
                    float s12 = ti.x * tj.y + ti.y * tj.x;
                    float cv = c12 * tl.x - s12 * tl.y;
                    float sv = c12 * tl.y + s12 * tl.x;
                    float4 s = srcs[a];
                    accC.x = fmaf(s.x, cv, accC.x); accC.y = fmaf(s.y, cv, accC.y);
                    accC.z = fmaf(s.z, cv, accC.z); accC.w = fmaf(s.w, cv, accC.w);
                    accS.x = fmaf(s.x, sv, accS.x); accS.y = fmaf(s.y, sv, accS.y);
                    accS.z = fmaf(s.z, sv, accS.z); accS.w = fmaf(s.w, sv, accS.w);
                }
            }
        }

        __syncthreads();
        if (h > 0) {
            partC[h - 1][kl] = accC;
            partS[h - 1][kl] = accS;
        }
        __syncthreads();
        if (h == 0 && kvalid) {
            #pragma unroll
            for (int q = 0; q < 3; ++q) {
                float4 pc = partC[q][kl], ps = partS[q][kl];
                accC.x += pc.x; accC.y += pc.y; accC.z += pc.z; accC.w += pc.w;
                accS.x += ps.x; accS.y += ps.y; accS.z += ps.z; accS.w += ps.w;
            }
            ((float4*)Sc)[b * KTOT + k] = accC;
            ((float4*)Ss)[b * KTOT + k] = accS;
        }
    }
}

// =================== K2: per-atom potential via i-plane recurrences ===================
__global__ __launch_bounds__(256) void kPot(
    const float* __restrict__ cell, const float* __restrict__ pos,
    const int* __restrict__ batch, const float* __restrict__ source,
    const float* __restrict__ wbuf,
    const float* __restrict__ Sc, const float* __restrict__ Ss,
    float* __restrict__ out)
{
    __shared__ float  lw[81];
    __shared__ float4 lSc[81];
    __shared__ float4 lSs[81];

    int b = blockIdx.x;
    int p = blockIdx.y;     // plane 0..8 -> i = p-4
    int tid = threadIdx.x;

    if (tid < 81) {
        int idx = p * 81 + tid;
        if (idx == 364) {   // excluded k=0 point
            lw[tid] = 0.f;
            lSc[tid] = make_float4(0.f, 0.f, 0.f, 0.f);
            lSs[tid] = make_float4(0.f, 0.f, 0.f, 0.f);
        } else {
            int k = idx - (idx > 364 ? 1 : 0);
            lw[tid]  = wbuf[b * KTOT + k];
            lSc[tid] = ((const float4*)Sc)[b * KTOT + k];
            lSs[tid] = ((const float4*)Ss)[b * KTOT + k];
        }
    }
    __syncthreads();

    int s0 = lower_bound_batch(batch, b);
    int e0 = lower_bound_batch(batch, b + 1);
    float fi = (float)(p - 4);

    float iv[9]; float det;
    inv3x3(cell + b * 9, iv, &det);

    for (int n = s0 + tid; n < e0; n += 256) {
        float px = pos[n * 3], py = pos[n * 3 + 1], pz = pos[n * 3 + 2];
        float p1 = TWO_PI * (px * iv[0] + py * iv[3] + pz * iv[6]);
        float p2 = TWO_PI * (px * iv[1] + py * iv[4] + pz * iv[7]);
        float p3 = TWO_PI * (px * iv[2] + py * iv[5] + pz * iv[8]);
        float4 s = ((const float4*)source)[n];

        float si0, ci0; sincosf(fi * p1, &si0, &ci0);
        float s2, c2;   sincosf(p2, &s2, &c2);
        float s3, c3;   sincosf(p3, &s3, &c3);

        float c2_2 = c2 * c2 - s2 * s2, s2_2 = 2.f * c2 * s2;
        float c2_4 = c2_2 * c2_2 - s2_2 * s2_2, s2_4 = 2.f * c2_2 * s2_2;
        float c3_2 = c3 * c3 - s3 * s3, s3_2 = 2.f * c3 * s3;
        float c3_4 = c3_2 * c3_2 - s3_2 * s3_2, s3_4 = 2.f * c3_2 * s3_2;

        float ejc = ci0 * c2_4 + si0 * s2_4;   // rot(i*p1) * rot(-4*p2)
        float ejs = si0 * c2_4 - ci0 * s2_4;

        float acc = 0.f;
        for (int jj = 0; jj < 9; ++jj) {
            float fc = ejc * c3_4 + ejs * s3_4; // ej * rot(-4*p3)
            float fs = ejs * c3_4 - ejc * s3_4;
            #pragma unroll
            for (int ll = 0; ll < 9; ++ll) {
                int e = jj * 9 + ll;
                float4 C  = lSc[e];
                float4 S4 = lSs[e];
                float w = lw[e];
                float dc = s.x * C.x  + s.y * C.y  + s.z * C.z  + s.w * C.w;
                float ds = s.x * S4.x + s.y * S4.y + s.z * S4.z + s.w * S4.w;
                acc = fmaf(w, fmaf(fc, dc, fs * ds), acc);
                float nfc = fc * c3 - fs * s3;
                fs = fc * s3 + fs * c3;
                fc = nfc;
            }
            float nejc = ejc * c2 - ejs * s2;
            ejs = ejc * s2 + ejs * c2;
            ejc = nejc;
        }
        atomicAdd(&out[n], acc);
    }
}

extern "C" void kernel_launch(void* const* d_in, const int* in_sizes, int n_in,
                              void* d_out, int out_size, void* d_ws, size_t ws_size,
                              hipStream_t stream)
{
    const float* pos    = (const float*)d_in[0];
    const int*   batch  = (const int*)d_in[1];
    const float* cell   = (const float*)d_in[2];
    const float* source = (const float*)d_in[3];
    const float* W1 = (const float*)d_in[4];
    const float* b1 = (const float*)d_in[5];
    const float* W2 = (const float*)d_in[6];
    const float* b2 = (const float*)d_in[7];
    const float* W3 = (const float*)d_in[8];
    const float* b3 = (const float*)d_in[9];
    float* out = (float*)d_out;

    float* ws   = (float*)d_ws;
    float* wbuf = ws;                  // 23296 floats
    float* Sc   = ws + 23296;          // 93184 floats (byte offset 93184, 16B aligned)
    float* Ss   = ws + 116480;         // 93184 floats

    kMain<<<dim3(483), 256, 0, stream>>>(cell, pos, batch, source,
        W1, b1, W2, b2, W3, b3, wbuf, Sc, Ss, out);
    kPot<<<dim3(NGRAPH, 9), 256, 0, stream>>>(cell, pos, batch, source,
        wbuf, Sc, Ss, out);
}